// Round 9
// baseline (82.748 us; speedup 1.0000x reference)
//
#include <hip/hip_runtime.h>
#include <math.h>

typedef unsigned int u32;
typedef unsigned long long u64;

#define BB 256
#define CC 28
#define DD 2048
#define KK 16
#define GA 14                    // max anchors/class: minority => m <= 14

// d_ws head: zeroed by a 16-byte memset node each call
struct Sync {
  float acc[2];                  // dp_total, dn_total
  u32 ticket;
  u32 pad;
};

// ---------------------------------------------------------------------------
// k_main: block (c, a) = class c, anchor-slot a. Fully fused:
//  counts (ballot) -> per-class activity -> total anchors -> rank-based
//  selection (verified exact in R4/R6: absmax 0) -> distances -> active-only
//  ticketed finalization (<=14 blocks touch the sync cacheline).
// ---------------------------------------------------------------------------
__global__ __launch_bounds__(256) void k_main(const float* __restrict__ inp,
                                              const int* __restrict__ target,
                                              const float* __restrict__ X,
                                              Sync* __restrict__ S,
                                              float* __restrict__ out) {
  const int c = blockIdx.x;
  const int a = blockIdx.y;
  const int tid = threadIdx.x;   // == row for the selection phase
  const int wave = tid >> 6, lane = tid & 63;

  __shared__ u32 s_bits[BB];     // inp[t][c] bits (non-negative: bit order == value order)
  __shared__ u32 s_pb[BB];       // row -> 28-bit positive mask
  __shared__ int s_cw[4][CC];
  __shared__ int s_counts[CC];
  __shared__ int s_act[CC];      // m if class active else 0
  __shared__ int s_pw[4];
  __shared__ int s_S[16], s_N[16], s_anchor;
  __shared__ float s_red[8];

  // --- row bitmask (coalesced int4) + own key ---
  u32 pb = 0;
  const int4* t4 = (const int4*)(target + tid * CC);
#pragma unroll
  for (int k = 0; k < 7; ++k) {
    int4 w = t4[k];
    pb |= (u32)(w.x != 0) << (4 * k) | (u32)(w.y != 0) << (4 * k + 1) |
          (u32)(w.z != 0) << (4 * k + 2) | (u32)(w.w != 0) << (4 * k + 3);
  }
  s_pb[tid] = pb;
  const u32 b = __float_as_uint(inp[tid * CC + c]);
  s_bits[tid] = b;

  // --- per-class counts via ballot ---
#pragma unroll
  for (int c2 = 0; c2 < CC; ++c2) {
    u64 bl = __ballot((pb >> c2) & 1u);
    if (lane == 0) s_cw[wave][c2] = __popcll(bl);
  }
  const int p = (pb >> c) & 1;
  const u64 bp = __ballot(p != 0);
  if (lane == 0) s_pw[wave] = __popcll(bp);
  __syncthreads();
  if (tid < CC)
    s_counts[tid] = s_cw[0][tid] + s_cw[1][tid] + s_cw[2][tid] + s_cw[3][tid];
  __syncthreads();

  // --- activity for ALL classes (thread t<28 handles class t) ---
  if (tid < CC) {
    const int mt = s_counts[tid];
    int cum = 0;
#pragma unroll
    for (int c2 = 0; c2 < CC; ++c2) {
      const int m2 = s_counts[c2];
      cum += (m2 < mt || (m2 == mt && c2 <= tid)) ? m2 : 0;
    }
    s_act[tid] = ((2 * cum <= CC) && (mt > 1)) ? mt : 0;
  }
  __syncthreads();

  const int m = s_counts[c];
  const bool active = (s_act[c] > 0) && (a < m);  // block-uniform
  int total = 0;                 // total active anchors (= Sum active m <= 14)
  if (tid == 0) {
#pragma unroll
    for (int c2 = 0; c2 < CC; ++c2) total += s_act[c2];
  }

  if (!active) {
    if (c == 0 && a == 0 && tid == 0 && total == 0)
      out[0] = 1.0f;             // relu(0 - 0 + margin)
    return;                      // no fence, no atomic: sync line untouched
  }

  // --- parallel rank selection (exact top_k tie semantics; R4-verified) ---
  int rank = 0;
  for (int j = 0; j < BB; ++j) {
    const u32 bj = s_bits[j];
    const int pj = (s_pb[j] >> c) & 1;
    const bool bpos = (bj < b) || (bj == b && j < tid);
    const bool bneg = (bj > b) || (bj == b && j < tid);
    rank += p ? ((pj && bpos) ? 1 : 0) : ((!pj && bneg) ? 1 : 0);
  }
  if (p) {
    if (rank < 16) s_S[rank] = tid;        // m <= 14: all positives land
    // row-order index among positives -> anchor ownership
    int idx = __popcll(bp & ((1ull << lane) - 1ull));
#pragma unroll
    for (int w2 = 0; w2 < 4; ++w2)
      if (w2 < wave) idx += s_pw[w2];
    if (idx == a) s_anchor = tid;
  } else {
    if (rank < KK) s_N[rank] = tid;
  }
  __syncthreads();

  const int anchor = s_anchor;
  const int NP = m - 1;                    // = min(K, m-1) since m <= 14
  const int NN = min(KK, BB - m);          // = 16
  int idx_a = 0;
  for (int u = 0; u < m; ++u)
    if (s_S[u] == anchor) idx_a = u;

  // anchor row in registers, coalesced float4
  const float4* Xa = (const float4*)(X + (size_t)anchor * DD);
  float4 A[8];
#pragma unroll
  for (int q = 0; q < 8; ++q) A[q] = Xa[q * 64 + lane];

  float dp = 0.f, dn = 0.f;
  for (int pidx = wave; pidx < NP + NN; pidx += 4) {
    const bool isdp = pidx < NP;
    const int j = isdp ? s_S[pidx + (pidx >= idx_a ? 1 : 0)] : s_N[pidx - NP];
    const float4* Xj = (const float4*)(X + (size_t)j * DD);
    float partial = 0.f;
#pragma unroll
    for (int q = 0; q < 8; ++q) {
      const float4 b4 = Xj[q * 64 + lane];
      partial += fabsf(A[q].x - b4.x) + fabsf(A[q].y - b4.y) +
                 fabsf(A[q].z - b4.z) + fabsf(A[q].w - b4.w);
    }
#pragma unroll
    for (int s = 1; s < 64; s <<= 1) partial += __shfl_xor(partial, s);
    if (isdp) dp += partial; else dn += partial;
  }
  if (lane == 0) { s_red[2 * wave] = dp; s_red[2 * wave + 1] = dn; }
  __syncthreads();

  // --- active-only ticketed finalization (<=14 participants) ---
  if (tid == 0) {
    const float dpT = s_red[0] + s_red[2] + s_red[4] + s_red[6];
    const float dnT = s_red[1] + s_red[3] + s_red[5] + s_red[7];
    atomicAdd(&S->acc[0], (float)NN * dpT);
    atomicAdd(&S->acc[1], (float)NP * dnT);
    __threadfence();
    const u32 tk = atomicAdd(&S->ticket, 1u);
    if (tk == (u32)(total - 1)) {          // last active block
      __threadfence();
      const float a0 = atomicAdd(&S->acc[0], 0.f);  // coherent reads
      const float a1 = atomicAdd(&S->acc[1], 0.f);
      out[0] = fmaxf(a0 - a1 + 1.0f, 0.0f);
    }
  }
}

extern "C" void kernel_launch(void* const* d_in, const int* in_sizes, int n_in,
                              void* d_out, int out_size, void* d_ws, size_t ws_size,
                              hipStream_t stream) {
  (void)in_sizes; (void)n_in; (void)out_size; (void)ws_size;
  const float* inp    = (const float*)d_in[0];  // [256,28] f32
  const int*   target = (const int*)d_in[1];    // [256,28] i32
  const float* X      = (const float*)d_in[2];  // [256,2048] f32
  float* out = (float*)d_out;
  Sync* S = (Sync*)d_ws;

  hipMemsetAsync(S, 0, sizeof(Sync), stream);   // graph-legal memset node
  k_main<<<dim3(CC, GA), 256, 0, stream>>>(inp, target, X, S, out);
}

// Round 12
// 81.166 us; speedup vs baseline: 1.0195x; 1.0195x over previous
//
#include <hip/hip_runtime.h>
#include <math.h>

typedef unsigned int u32;
typedef unsigned long long u64;

#define BB 256
#define CC 28
#define DD 2048
#define KK 16
#define GA 14                    // max anchors/class: minority => m <= 14

// ---------------------------------------------------------------------------
// k_all: block (c, a) = class c, anchor-slot a. Fully fused, ZERO fences and
// ZERO atomics (R9 post-mortem: device-scope fences trigger ~10us of dirty-L2
// writeback from the harness poison fill; R4/R9 both paid it).
//  counts (ballot) -> per-class activity (cumsum rule) -> rank-based top-k
//  selection (absmax-0-verified in R4/R6/R9) -> L1 distances (anchor row in
//  registers) -> private part[] slot write per block (deterministic).
// ---------------------------------------------------------------------------
__global__ __launch_bounds__(256) void k_all(const float* __restrict__ inp,
                                             const int* __restrict__ target,
                                             const float* __restrict__ X,
                                             float* __restrict__ part) {
  const int c = blockIdx.x;
  const int a = blockIdx.y;
  const int tid = threadIdx.x;   // == row for the selection phase
  const int wave = tid >> 6, lane = tid & 63;

  __shared__ u32 s_bits[BB];     // inp[t][c] bits (uniform[0,1): bit order == value order)
  __shared__ u32 s_pb[BB];       // row -> 28-bit positive mask
  __shared__ int s_cw[4][CC];
  __shared__ int s_counts[CC];
  __shared__ int s_S[16], s_N[16], s_anchor;
  __shared__ int s_pw[4];
  __shared__ float s_red[8];

  // --- row bitmask (coalesced int4) + own key ---
  u32 pb = 0;
  const int4* t4 = (const int4*)(target + tid * CC);
#pragma unroll
  for (int k = 0; k < 7; ++k) {
    int4 w = t4[k];
    pb |= (u32)(w.x != 0) << (4 * k) | (u32)(w.y != 0) << (4 * k + 1) |
          (u32)(w.z != 0) << (4 * k + 2) | (u32)(w.w != 0) << (4 * k + 3);
  }
  s_pb[tid] = pb;
  const u32 b = __float_as_uint(inp[tid * CC + c]);
  s_bits[tid] = b;

  // --- per-class counts via ballot ---
#pragma unroll
  for (int c2 = 0; c2 < CC; ++c2) {
    u64 bl = __ballot((pb >> c2) & 1u);
    if (lane == 0) s_cw[wave][c2] = __popcll(bl);
  }
  const int p = (pb >> c) & 1;
  const u64 bp = __ballot(p != 0);
  if (lane == 0) s_pw[wave] = __popcll(bp);
  __syncthreads();
  if (tid < CC)
    s_counts[tid] = s_cw[0][tid] + s_cw[1][tid] + s_cw[2][tid] + s_cw[3][tid];
  __syncthreads();

  // --- minority(c): stable-argsort cumsum rule (lex on (count, index)) ---
  const int m = s_counts[c];
  int cum = 0;
#pragma unroll
  for (int c2 = 0; c2 < CC; ++c2) {
    const int m2 = s_counts[c2];
    cum += (m2 < m || (m2 == m && c2 <= c)) ? m2 : 0;
  }
  const bool active = (2 * cum <= CC) && (m > 1) && (a < m);  // block-uniform

  if (!active) {
    if (tid == 0) {  // ws is poisoned: must write zeros
      part[2 * (c * GA + a)] = 0.f;
      part[2 * (c * GA + a) + 1] = 0.f;
    }
    return;
  }

  // --- parallel rank selection (exact top_k tie semantics) ---
  int rank = 0;
  for (int j = 0; j < BB; ++j) {
    const u32 bj = s_bits[j];
    const int pj = (s_pb[j] >> c) & 1;
    const bool bpos = (bj < b) || (bj == b && j < tid);
    const bool bneg = (bj > b) || (bj == b && j < tid);
    rank += p ? ((pj && bpos) ? 1 : 0) : ((!pj && bneg) ? 1 : 0);
  }
  if (p) {
    if (rank < 16) s_S[rank] = tid;        // m <= 14: all positives land
    // row-order index among positives -> anchor ownership
    int idx = __popcll(bp & ((1ull << lane) - 1ull));
#pragma unroll
    for (int w2 = 0; w2 < 4; ++w2)
      if (w2 < wave) idx += s_pw[w2];
    if (idx == a) s_anchor = tid;
  } else {
    if (rank < KK) s_N[rank] = tid;
  }
  __syncthreads();

  const int anchor = s_anchor;
  const int NP = m - 1;                    // = min(K, m-1) since m <= 14
  const int NN = min(KK, BB - m);          // = 16
  int idx_a = 0;
  for (int u = 0; u < m; ++u)
    if (s_S[u] == anchor) idx_a = u;

  // anchor row in registers, coalesced float4
  const float4* Xa = (const float4*)(X + (size_t)anchor * DD);
  float4 A[8];
#pragma unroll
  for (int q = 0; q < 8; ++q) A[q] = Xa[q * 64 + lane];

  float dp = 0.f, dn = 0.f;
  for (int pidx = wave; pidx < NP + NN; pidx += 4) {
    const bool isdp = pidx < NP;
    const int j = isdp ? s_S[pidx + (pidx >= idx_a ? 1 : 0)] : s_N[pidx - NP];
    const float4* Xj = (const float4*)(X + (size_t)j * DD);
    float partial = 0.f;
#pragma unroll
    for (int q = 0; q < 8; ++q) {
      const float4 b4 = Xj[q * 64 + lane];
      partial += fabsf(A[q].x - b4.x) + fabsf(A[q].y - b4.y) +
                 fabsf(A[q].z - b4.z) + fabsf(A[q].w - b4.w);
    }
#pragma unroll
    for (int s = 1; s < 64; s <<= 1) partial += __shfl_xor(partial, s);
    if (isdp) dp += partial; else dn += partial;
  }
  if (lane == 0) { s_red[2 * wave] = dp; s_red[2 * wave + 1] = dn; }
  __syncthreads();

  if (tid == 0) {
    part[2 * (c * GA + a)]     = (float)NN * (s_red[0] + s_red[2] + s_red[4] + s_red[6]);
    part[2 * (c * GA + a) + 1] = (float)NP * (s_red[1] + s_red[3] + s_red[5] + s_red[7]);
  }
}

// ---------------------------------------------------------------------------
// k_final: sum the 392 partial pairs, apply margin + relu.
// (All-inactive case: sums are 0 -> relu(0-0+1) = 1, correct.)
// ---------------------------------------------------------------------------
__global__ __launch_bounds__(256) void k_final(const float* __restrict__ part,
                                               float* __restrict__ out) {
  const int tid = threadIdx.x;
  const int wave = tid >> 6, lane = tid & 63;
  __shared__ float s_red[8];

  float dp = 0.f, dn = 0.f;
  for (int t = tid; t < CC * GA; t += 256) {
    dp += part[2 * t];
    dn += part[2 * t + 1];
  }
#pragma unroll
  for (int s = 1; s < 64; s <<= 1) {
    dp += __shfl_xor(dp, s);
    dn += __shfl_xor(dn, s);
  }
  if (lane == 0) { s_red[2 * wave] = dp; s_red[2 * wave + 1] = dn; }
  __syncthreads();
  if (tid == 0) {
    const float dpT = s_red[0] + s_red[2] + s_red[4] + s_red[6];
    const float dnT = s_red[1] + s_red[3] + s_red[5] + s_red[7];
    out[0] = fmaxf(dpT - dnT + 1.0f, 0.0f);
  }
}

extern "C" void kernel_launch(void* const* d_in, const int* in_sizes, int n_in,
                              void* d_out, int out_size, void* d_ws, size_t ws_size,
                              hipStream_t stream) {
  (void)in_sizes; (void)n_in; (void)out_size; (void)ws_size;
  const float* inp    = (const float*)d_in[0];  // [256,28] f32
  const int*   target = (const int*)d_in[1];    // [256,28] i32
  const float* X      = (const float*)d_in[2];  // [256,2048] f32
  float* out = (float*)d_out;
  float* part = (float*)d_ws;                   // [392][2] private slots

  k_all<<<dim3(CC, GA), 256, 0, stream>>>(inp, target, X, part);
  k_final<<<1, 256, 0, stream>>>(part, out);
}